// Round 7
// baseline (133.462 us; speedup 1.0000x reference)
//
#include <hip/hip_runtime.h>
#include <hip/hip_bf16.h>

#define NPTS 524288
#define DIM 256
#define KC 64

typedef __attribute__((ext_vector_type(8))) short bf16x8;
typedef __attribute__((ext_vector_type(4))) float f32x4;

typedef __attribute__((address_space(1))) const unsigned int GUI;
typedef __attribute__((address_space(3))) unsigned int LUI;

static __device__ __forceinline__ void gload16(const void* g, void* l) {
  __builtin_amdgcn_global_load_lds((GUI*)g, (LUI*)l, 16, 0, 0);
}

static __device__ __forceinline__ ushort f32_to_bf16_rne(float f) {
  unsigned int b = __builtin_bit_cast(unsigned int, f);
  b += 0x7FFFu + ((b >> 16) & 1u);   // RNE; inputs finite
  return (ushort)(b >> 16);
}

static __device__ __forceinline__ short f2bf(float f) {
  return __builtin_bit_cast(short, __float2bfloat16(f));  // pairs fuse to cvt_pk
}

static __device__ __forceinline__ f32x4 ntld(const void* p) {
  return __builtin_nontemporal_load((const f32x4*)p);  // read-once
}

// ws image (32 KiB): slot s holds cluster 4*(s%16)+s/16; 16-B granule m of slot s
// lives at byte s*512 + ((m ^ (s&7))<<4). c2 (natural cluster order) at +32768.
__global__ void prep_clusters(const float* __restrict__ C,
                              char* __restrict__ cb,
                              float* __restrict__ c2) {
  const int w = threadIdx.x >> 6;
  const int lane = threadIdx.x & 63;
  const int k = blockIdx.x * 8 + w * 2 + (lane >> 5);  // cluster
  const int m = lane & 31;                             // 16-B granule (8 elems)
  const float* src = C + k * DIM + m * 8;
  float4 u0 = ((const float4*)src)[0];
  float4 u1 = ((const float4*)src)[1];
  float vv[8] = {u0.x, u0.y, u0.z, u0.w, u1.x, u1.y, u1.z, u1.w};
  float s = 0.f;
  bf16x8 h;
#pragma unroll
  for (int j = 0; j < 8; ++j) {
    s = fmaf(vv[j], vv[j], s);
    h[j] = (short)f32_to_bf16_rne(vv[j]);
  }
  s += __shfl_xor(s, 1);
  s += __shfl_xor(s, 2);
  s += __shfl_xor(s, 4);
  s += __shfl_xor(s, 8);
  s += __shfl_xor(s, 16);
  const int slot = 16 * (k & 3) + (k >> 2);
  const int off = slot * 512 + ((m ^ (slot & 7)) << 4);
  *(bf16x8*)(cb + off) = h;
  if (m == 0) c2[k] = s;
}

// Block: 4 waves, 64 rows (16/wave), 64 cols. LDS = 32 KiB (B only) -> 4 blocks/CU.
// A: ALL 16 per-lane loads (the wave's full 16 KB, contiguous) issued as one
// back-to-back batch pinned by sched_barrier fences -> dense request cluster at
// the memory controller (DRAM page locality; ~1 activate/KB instead of ~8).
// Counted barrier: vmcnt(16) certifies the 8 L2 B-gloads; A stays in flight.
// Compiler's own fine-grained vmcnt(N) releases KSTEP k when av[2k..2k+1] land.
__global__ __launch_bounds__(256, 4)
void cluster_q(const float* __restrict__ A, const char* __restrict__ cb,
               const float* __restrict__ c2, float* __restrict__ out) {
  __shared__ char lds[32768];
  const int tid = threadIdx.x;
  const int lane = tid & 63;
  const int w = tid >> 6;
  const int l15 = lane & 15;
  const int g = lane >> 4;
  const long brow = (long)blockIdx.x * 64;

  // lane (l15,g) owns row (w*16+l15), bytes ks*128 + g*32 .. +32 per K-step
  const char* Ap = (const char*)A + (brow + w * 16 + l15) * 1024 + g * 32;

  // ---- B stage (L2-resident ws image, linear gload16) -- first in VMEM queue
  {
    const char* src = cb + w * 8192 + lane * 16;
    char* dst = lds + w * 8192;
#pragma unroll
    for (int i = 0; i < 8; ++i)
      gload16(src + i * 1024, dst + i * 1024);
  }
  __builtin_amdgcn_sched_barrier(0);

  // ---- the wave's ENTIRE A tile: 16 loads back-to-back (16 KB contiguous)
  f32x4 av[16];
#pragma unroll
  for (int k2 = 0; k2 < 16; ++k2)
    av[k2] = ntld(Ap + (k2 >> 1) * 128 + (k2 & 1) * 16);
  __builtin_amdgcn_sched_barrier(0);

  asm volatile("s_waitcnt vmcnt(16)" ::: "memory");  // B done; A in flight
  __builtin_amdgcn_s_barrier();
  __builtin_amdgcn_sched_barrier(0);

  f32x4 acc[4];
#pragma unroll
  for (int t = 0; t < 4; ++t) acc[t] = (f32x4){0.f, 0.f, 0.f, 0.f};
  float x2l = 0.f;

#define KSTEP(ks)                                                            \
  do {                                                                       \
    f32x4 CA = av[2 * (ks)];                                                 \
    f32x4 CB = av[2 * (ks) + 1];                                             \
    float vv[8] = {CA[0], CA[1], CA[2], CA[3], CB[0], CB[1], CB[2], CB[3]};  \
    bf16x8 af;                                                               \
    _Pragma("unroll") for (int j2 = 0; j2 < 8; ++j2) {                       \
      x2l = fmaf(vv[j2], vv[j2], x2l);                                       \
      af[j2] = f2bf(vv[j2]);                                                 \
    }                                                                        \
    _Pragma("unroll") for (int t = 0; t < 4; ++t) {                          \
      int slot = l15 + 16 * t;                                               \
      bf16x8 bf = *(const bf16x8*)(lds + slot * 512 +                        \
                                   ((((ks) * 4 + g) ^ (slot & 7)) << 4));    \
      acc[t] = __builtin_amdgcn_mfma_f32_16x16x32_bf16(af, bf, acc[t], 0, 0, 0); \
    }                                                                        \
  } while (0)

  KSTEP(0); KSTEP(1); KSTEP(2); KSTEP(3);
  KSTEP(4); KSTEP(5); KSTEP(6); KSTEP(7);
#undef KSTEP

  // ---- epilogue
  x2l += __shfl_xor(x2l, 16);
  x2l += __shfl_xor(x2l, 32);  // full ||x||^2 for row l15, replicated across g
  float x2r[4];
#pragma unroll
  for (int r = 0; r < 4; ++r) x2r[r] = __shfl(x2l, g * 4 + r);

  float4 c2v = *(const float4*)(c2 + 4 * l15);  // clusters 4*l15 .. +3 (== t)
  float c2a[4] = {c2v.x, c2v.y, c2v.z, c2v.w};

  float qv[4][4];
  float rsum[4] = {0.f, 0.f, 0.f, 0.f};
#pragma unroll
  for (int t = 0; t < 4; ++t) {
#pragma unroll
    for (int r = 0; r < 4; ++r) {
      float d2 = fmaxf(x2r[r] + c2a[t] - 2.0f * acc[t][r], 0.f);
      float qq = __builtin_amdgcn_rcpf(1.0f + d2);  // ALPHA=1, exponent 1
      qv[t][r] = qq;
      rsum[r] += qq;
    }
  }
#pragma unroll
  for (int r = 0; r < 4; ++r) {
    rsum[r] += __shfl_xor(rsum[r], 1);
    rsum[r] += __shfl_xor(rsum[r], 2);
    rsum[r] += __shfl_xor(rsum[r], 4);
    rsum[r] += __shfl_xor(rsum[r], 8);
    float inv = __builtin_amdgcn_rcpf(rsum[r]);
    long orow = brow + w * 16 + g * 4 + r;
    f32x4 o4 = {qv[0][r] * inv, qv[1][r] * inv, qv[2][r] * inv, qv[3][r] * inv};
    __builtin_nontemporal_store(o4, (f32x4*)(out + orow * 64 + 4 * l15));
  }
}

extern "C" void kernel_launch(void* const* d_in, const int* in_sizes, int n_in,
                              void* d_out, int out_size, void* d_ws, size_t ws_size,
                              hipStream_t stream) {
  const float* inputs = (const float*)d_in[0];
  const float* clusters = (const float*)d_in[1];
  float* out = (float*)d_out;

  char* cb = (char*)d_ws;                      // 32 KiB pre-swizzled B image
  float* c2 = (float*)((char*)d_ws + 32768);   // 64 floats

  prep_clusters<<<8, 256, 0, stream>>>(clusters, cb, c2);
  cluster_q<<<NPTS / 64, 256, 0, stream>>>(inputs, cb, c2, out);
}